// Round 1
// 159.120 us; speedup vs baseline: 1.0288x; 1.0288x over previous
//
#include <hip/hip_runtime.h>

// VisionPooler: 3x3 mean-pool over 48x48 patch grid, x sqrt(768).
// B=16, G=48, D=768, K=3  ->  N=2304 patches, L=256 bins.
// Output: [B*L, D] f32 pooled, then [B*L] valid_mask (all-True -> 1.0f).
//
// Pure streaming kernel: 113.2 MB read once + 12.6 MB written once.
// This revision marks both streams non-temporal (nt bit on global_load/store)
// to skip L2 allocate/evict churn for data with zero reuse.

#define B  16
#define G  48
#define D  768
#define NN (G * G)           // 2304 patches per image
#define LL 256               // output bins per image
#define D4 (D / 4)           // 192 float4 per row
#define OUT_ELEMS (B * LL * D)

typedef float f32x4 __attribute__((ext_vector_type(4)));

// One block per (b, bin). 192 threads = 3 waves; thread t owns float4 #t of D.
// Each bin = mean of 9 patch rows: 3 grid rows (r) of 3 consecutive patches (c).
// All 9 loads issued before any arithmetic -> 144 B in flight per thread.
__global__ __launch_bounds__(192) void pool_kernel(const float* __restrict__ h,
                                                   float* __restrict__ out,
                                                   int n_mask) {
    const int bl = blockIdx.x;          // 0 .. B*LL-1
    const int b  = bl >> 8;             // image
    const int l  = bl & 255;            // bin
    const int kx = l & 15;              // bin column (16 per grid row)
    const int ky = l >> 4;              // bin row
    const int t  = threadIdx.x;         // 0..191

    const f32x4* __restrict__ base =
        reinterpret_cast<const f32x4*>(h) + (size_t)b * NN * D4 + t;

    // Row starts of the 3 patch rows feeding this bin (each 3 patches contiguous).
    const size_t n0 = (size_t)((3 * ky) * G + 3 * kx) * D4;
    const size_t rowstride = (size_t)G * D4;

    const f32x4* p0 = base + n0;
    const f32x4* p1 = p0 + rowstride;
    const f32x4* p2 = p1 + rowstride;

    // Non-temporal: single-use stream, don't allocate in cache hierarchy.
    f32x4 v0 = __builtin_nontemporal_load(p0);
    f32x4 v1 = __builtin_nontemporal_load(p0 + D4);
    f32x4 v2 = __builtin_nontemporal_load(p0 + 2 * D4);
    f32x4 v3 = __builtin_nontemporal_load(p1);
    f32x4 v4 = __builtin_nontemporal_load(p1 + D4);
    f32x4 v5 = __builtin_nontemporal_load(p1 + 2 * D4);
    f32x4 v6 = __builtin_nontemporal_load(p2);
    f32x4 v7 = __builtin_nontemporal_load(p2 + D4);
    f32x4 v8 = __builtin_nontemporal_load(p2 + 2 * D4);

    // Tree-sum (elementwise on the native vector type).
    f32x4 acc = ((v0 + v1) + (v2 + v3)) + ((v4 + v5) + (v6 + v7)) + v8;

    const float s = 3.0792014356780038f;   // sqrt(768) / 9
    f32x4 o = acc * s;
    __builtin_nontemporal_store(o, reinterpret_cast<f32x4*>(out) + (size_t)bl * D4 + t);

    // Fused valid_mask write: one element per block, all-True by construction.
    if (t == 0 && bl < n_mask) {
        out[(size_t)OUT_ELEMS + bl] = 1.0f;
    }
}

extern "C" void kernel_launch(void* const* d_in, const int* in_sizes, int n_in,
                              void* d_out, int out_size, void* d_ws, size_t ws_size,
                              hipStream_t stream) {
    const float* h = (const float*)d_in[0];
    float* out = (float*)d_out;
    const int n_mask = out_size - OUT_ELEMS;   // expected B*LL = 4096

    pool_kernel<<<B * LL, 192, 0, stream>>>(h, out, n_mask);
}